// Round 22
// baseline (52.336 us; speedup 1.0000x reference)
//
#include <hip/hip_runtime.h>
#include <hip/hip_bf16.h>

#define DDIM   256    // K (feature dim)
#define BROWS  256    // block output rows (4 waves x 64 rows)
#define BCH    256    // cols per block chunk (8 phases x 32)
#define SQRT_LOG2E 1.2011224087864498f   // sqrt(log2(e)); dot *= log2(e)

typedef float f32x4 __attribute__((ext_vector_type(4)));
typedef int   i32x4 __attribute__((ext_vector_type(4)));
typedef int   i32x8 __attribute__((ext_vector_type(8)));

// v_exp_f32: D = 2^S0 (hardware transcendental)
__device__ __forceinline__ float exp2_hw(float x) {
  return __builtin_amdgcn_exp2f(x);
}

// MX-scaled fp8 MFMA, unit scales (E8M0 127 = 1.0). cbsz=0/blgp=0 -> e4m3.
__device__ __forceinline__ f32x4 mfma_mx(i32x8 a, i32x8 b, f32x4 c) {
  return __builtin_amdgcn_mfma_scale_f32_16x16x128_f8f6f4(
      a, b, c, 0, 0, 0, 0x7F7F7F7F, 0, 0x7F7F7F7F);
}

__device__ __forceinline__ i32x8 cat8(i32x4 lo, i32x4 hi) {
  return __builtin_shufflevector(lo, hi, 0, 1, 2, 3, 4, 5, 6, 7);
}

// pack 4 f32 -> 4 fp8 e4m3 bytes
__device__ __forceinline__ unsigned int pack4_fp8(float a0, float a1, float a2, float a3) {
  int v = __builtin_amdgcn_cvt_pk_fp8_f32(a0, a1, 0, false);   // bytes 0,1
  v = __builtin_amdgcn_cvt_pk_fp8_f32(a2, a3, v, true);        // bytes 2,3
  return (unsigned int)v;
}

// ---- prep: one wave per row; writes sqrt(log2e)-scaled UNIT-NORM fp8 rows
// (so the GEMM dot is s*log2e and the epilogue is a bare exp2) + exact diag.
__global__ __launch_bounds__(256) void prep_kernel(
    const float* __restrict__ q, const float* __restrict__ r,
    unsigned char* __restrict__ qf8, unsigned char* __restrict__ rf8,
    float* __restrict__ pos, float* __restrict__ row_sum,
    float* __restrict__ out) {
  if (blockIdx.x == 0 && threadIdx.x == 0) out[0] = 0.0f;  // finalize atomics
  int lane = threadIdx.x & 63, wave = threadIdx.x >> 6;
  int row = blockIdx.x * 4 + wave;
  size_t base = (size_t)row * DDIM + lane * 4;
  float4 qv = *(const float4*)(q + base);
  float4 rv = *(const float4*)(r + base);
  float qq = qv.x*qv.x + qv.y*qv.y + qv.z*qv.z + qv.w*qv.w;
  float rr = rv.x*rv.x + rv.y*rv.y + rv.z*rv.z + rv.w*rv.w;
  float qr = qv.x*rv.x + qv.y*rv.y + qv.z*rv.z + qv.w*rv.w;
  #pragma unroll
  for (int m = 1; m < 64; m <<= 1) {
    qq += __shfl_xor(qq, m);
    rr += __shfl_xor(rr, m);
    qr += __shfl_xor(qr, m);
  }
  float iq0 = 1.0f / sqrtf(qq);
  float ir0 = 1.0f / sqrtf(rr);
  float iq = iq0 * SQRT_LOG2E;
  float ir = ir0 * SQRT_LOG2E;
  unsigned int qp = pack4_fp8(qv.x*iq, qv.y*iq, qv.z*iq, qv.w*iq);
  unsigned int rp = pack4_fp8(rv.x*ir, rv.y*ir, rv.z*ir, rv.w*ir);
  *(unsigned int*)(qf8 + base) = qp;
  *(unsigned int*)(rf8 + base) = rp;
  if (lane == 0) {
    pos[row] = qr * iq0 * ir0;   // exact f32 diagonal from raw inputs
    row_sum[row] = 0.0f;
  }
}

// LDS-FREE MX-K128 GEMM+LSE. With 16x16x128 MFMA, a wave-phase needs only
// 16 x 16B B-fragment loads — small enough that B comes straight from L1
// (each fragment re-read by the block's 4 waves; 16 KB/phase tile is
// L1-hot). No LDS, no barriers, no vmcnt choreography: every wave is an
// independent pipeline and 3 waves/SIMD hide each other's latencies.
// Register total ~146 (114 arch + 32 AGPR) -> fits the (256,2) budget
// (the rule from R5-R20: bounds (x,2) -> 128-arch budget; this was
// infeasible in R12's bf16 era when demand was 190).
__global__ __launch_bounds__(256, 2) void gemm_lse_kernel(
    const unsigned char* __restrict__ qf8, const unsigned char* __restrict__ rf8,
    float* __restrict__ row_sum) {
  const int tid  = threadIdx.x;
  const int lane = tid & 63;
  const int wid  = tid >> 6;            // 4 waves, each owns 64 rows
  const int g = lane >> 4, c = lane & 15;
  const int row0  = blockIdx.x * BROWS;
  const int col00 = blockIdx.y * BCH;

  // A fragments -> registers (4 row-frags x 2 K-halves x 8 i32 = 64 VGPR),
  // read once. 16x16x128 A-operand: lane holds bytes [g*32, g*32+32) of
  // each 128-K half at row lane&15 (validated R16-R19).
  i32x8 av[4][2];
  const char* Ab = (const char*)qf8;
  #pragma unroll
  for (int m = 0; m < 4; ++m) {
    size_t rb0 = (size_t)(row0 + wid * 64 + m * 16 + c) * 256;
    #pragma unroll
    for (int h = 0; h < 2; ++h) {
      const char* p = Ab + rb0 + h * 128 + g * 32;
      av[m][h] = cat8(*(const i32x4*)(p), *(const i32x4*)(p + 16));
    }
  }

  // per-lane B base: column (col00 + c), this lane's 32B K-slice
  const char* b0 = (const char*)rf8 + (size_t)(col00 + c) * 256 + g * 32;

  float rs[16];
  #pragma unroll
  for (int k = 0; k < 16; ++k) rs[k] = 0.0f;

  #pragma unroll 1      // R18 lesson: unrolling blows the live-range budget
  for (int p = 0; p < BCH / 32; ++p) {
    const char* bp = b0 + p * 32 * 256;   // cols p*32 + {c, 16+c}

    // B fragments straight from global (L1-hot: same 16 fragments are read
    // by all 4 waves of the block). cf = col-fragment, h = K-half.
    i32x8 bv[2][2];
    #pragma unroll
    for (int cf = 0; cf < 2; ++cf)
      #pragma unroll
      for (int h = 0; h < 2; ++h) {
        const char* a = bp + cf * 16 * 256 + h * 128;
        bv[cf][h] = cat8(*(const i32x4*)(a), *(const i32x4*)(a + 16));
      }

    f32x4 acc[4][2];
    const f32x4 zero = {0.f, 0.f, 0.f, 0.f};
    #pragma unroll
    for (int m = 0; m < 4; ++m) { acc[m][0] = zero; acc[m][1] = zero; }
    __builtin_amdgcn_s_setprio(1);
    #pragma unroll
    for (int m = 0; m < 4; ++m)
      #pragma unroll
      for (int cf = 0; cf < 2; ++cf) {
        acc[m][cf] = mfma_mx(av[m][0], bv[cf][0], acc[m][cf]);
        acc[m][cf] = mfma_mx(av[m][1], bv[cf][1], acc[m][cf]);
      }
    __builtin_amdgcn_s_setprio(0);

    // dot already includes log2(e): bare exp2. C layout: col = p*32+cf*16+c,
    // row = m*16 + g*4 + jj (validated R16-R19).
    #pragma unroll
    for (int m = 0; m < 4; ++m)
      #pragma unroll
      for (int jj = 0; jj < 4; ++jj)
        rs[m * 4 + jj] += exp2_hw(acc[m][0][jj]) + exp2_hw(acc[m][1][jj]);
  }

  // reduce the 16 column-lanes holding the same row, one atomic per row
  #pragma unroll
  for (int k = 0; k < 16; ++k) {
    float v = rs[k];
    v += __shfl_xor(v, 1);
    v += __shfl_xor(v, 2);
    v += __shfl_xor(v, 4);
    v += __shfl_xor(v, 8);
    if (c == 0) {
      int row = row0 + wid * 64 + (k >> 2) * 16 + g * 4 + (k & 3);
      atomicAdd(&row_sum[row], v);
    }
  }
}

// 32 blocks x 256 threads, one row per thread, one atomicAdd per block
// (prep zeroed out[0]).
__global__ __launch_bounds__(256) void finalize_kernel(
    const float* __restrict__ row_sum, const float* __restrict__ pos,
    float* __restrict__ out) {
  int i = blockIdx.x * 256 + threadIdx.x;
  float s = __logf(row_sum[i]) - pos[i];
  #pragma unroll
  for (int m = 1; m < 64; m <<= 1) s += __shfl_xor(s, m);
  __shared__ float red[4];
  if ((threadIdx.x & 63) == 0) red[threadIdx.x >> 6] = s;
  __syncthreads();
  if (threadIdx.x == 0)
    atomicAdd(out, red[0] + red[1] + red[2] + red[3]);  // -loss = sum(lse-pos)
}

extern "C" void kernel_launch(void* const* d_in, const int* in_sizes, int n_in,
                              void* d_out, int out_size, void* d_ws, size_t ws_size,
                              hipStream_t stream) {
  const float* q = (const float*)d_in[0];
  const float* r = (const float*)d_in[1];
  int n = in_sizes[0] / DDIM;  // 8192

  char* w = (char*)d_ws;
  size_t f8Bytes = (size_t)n * DDIM;
  unsigned char* qf8 = (unsigned char*)w;
  unsigned char* rf8 = (unsigned char*)(w + f8Bytes);
  float* pos     = (float*)(w + 2 * f8Bytes);
  float* row_sum = pos + n;

  prep_kernel<<<n / 4, 256, 0, stream>>>(q, r, qf8, rf8, pos, row_sum,
                                         (float*)d_out);

  dim3 grid(n / BROWS, n / BCH);   // 32 x 32 = 1024 blocks, no LDS cap
  gemm_lse_kernel<<<grid, 256, 0, stream>>>(qf8, rf8, row_sum);

  finalize_kernel<<<n / 256, 256, 0, stream>>>(row_sum, pos, (float*)d_out);
}

// Round 23
// 38.312 us; speedup vs baseline: 1.3660x; 1.3660x over previous
//
#include <hip/hip_runtime.h>
#include <hip/hip_bf16.h>

#define DDIM   256    // K (feature dim)
#define BROWS  128    // block output rows (4 waves x 32 rows)
#define BN      64    // cols per N-tile
#define NT       8    // N-tiles per block -> 512-col chunk
#define TS   (BN * DDIM)   // 16 KB per buffer
#define SQRT_LOG2E 1.2011224087864498f   // sqrt(log2(e)); dot *= log2(e)

typedef float f32x4 __attribute__((ext_vector_type(4)));
typedef int   i32x4 __attribute__((ext_vector_type(4)));
typedef int   i32x8 __attribute__((ext_vector_type(8)));

// v_exp_f32: D = 2^S0 (hardware transcendental)
__device__ __forceinline__ float exp2_hw(float x) {
  return __builtin_amdgcn_exp2f(x);
}

// MX-scaled fp8 MFMA, unit scales (E8M0 127 = 1.0). cbsz=0/blgp=0 -> e4m3.
__device__ __forceinline__ f32x4 mfma_mx(i32x8 a, i32x8 b, f32x4 c) {
  return __builtin_amdgcn_mfma_scale_f32_16x16x128_f8f6f4(
      a, b, c, 0, 0, 0, 0x7F7F7F7F, 0, 0x7F7F7F7F);
}

__device__ __forceinline__ i32x8 cat8(i32x4 lo, i32x4 hi) {
  return __builtin_shufflevector(lo, hi, 0, 1, 2, 3, 4, 5, 6, 7);
}

// pack 4 f32 -> 4 fp8 e4m3 bytes
__device__ __forceinline__ unsigned int pack4_fp8(float a0, float a1, float a2, float a3) {
  int v = __builtin_amdgcn_cvt_pk_fp8_f32(a0, a1, 0, false);   // bytes 0,1
  v = __builtin_amdgcn_cvt_pk_fp8_f32(a2, a3, v, true);        // bytes 2,3
  return (unsigned int)v;
}

// ---- prep: one wave per row; writes sqrt(log2e)-scaled UNIT-NORM fp8 rows
// (so the GEMM dot is s*log2e and the epilogue is a bare exp2) + exact diag.
__global__ __launch_bounds__(256) void prep_kernel(
    const float* __restrict__ q, const float* __restrict__ r,
    unsigned char* __restrict__ qf8, unsigned char* __restrict__ rf8,
    float* __restrict__ pos, float* __restrict__ row_sum,
    float* __restrict__ out) {
  if (blockIdx.x == 0 && threadIdx.x == 0) out[0] = 0.0f;  // finalize atomics
  int lane = threadIdx.x & 63, wave = threadIdx.x >> 6;
  int row = blockIdx.x * 4 + wave;
  size_t base = (size_t)row * DDIM + lane * 4;
  float4 qv = *(const float4*)(q + base);
  float4 rv = *(const float4*)(r + base);
  float qq = qv.x*qv.x + qv.y*qv.y + qv.z*qv.z + qv.w*qv.w;
  float rr = rv.x*rv.x + rv.y*rv.y + rv.z*rv.z + rv.w*rv.w;
  float qr = qv.x*rv.x + qv.y*rv.y + qv.z*rv.z + qv.w*rv.w;
  #pragma unroll
  for (int m = 1; m < 64; m <<= 1) {
    qq += __shfl_xor(qq, m);
    rr += __shfl_xor(rr, m);
    qr += __shfl_xor(qr, m);
  }
  float iq0 = 1.0f / sqrtf(qq);
  float ir0 = 1.0f / sqrtf(rr);
  float iq = iq0 * SQRT_LOG2E;
  float ir = ir0 * SQRT_LOG2E;
  unsigned int qp = pack4_fp8(qv.x*iq, qv.y*iq, qv.z*iq, qv.w*iq);
  unsigned int rp = pack4_fp8(rv.x*ir, rv.y*ir, rv.z*ir, rv.w*ir);
  *(unsigned int*)(qf8 + base) = qp;
  *(unsigned int*)(rf8 + base) = rp;
  if (lane == 0) {
    pos[row] = qr * iq0 * ir0;   // exact f32 diagonal from raw inputs
    row_sum[row] = 0.0f;
  }
}

// stage quarter q of a 64-col fp8 tile: 1 load/thread into the LANE-LINEAR
// layout (R17-validated): chunk (col=p*32+cf*16+c, k16=h*8+g*2+pc) at index
// (p*8+cf*4+h*2+pc)*64 + (g*16+c) -> all ds_reads are base+lane*16+imm,
// zero bank conflicts. SOURCE applies the inverse permutation (rule 21).
__device__ __forceinline__ void stage_quarter(char* dstBase,
                                              const unsigned char* src_base,
                                              int col0, int q, int tid) {
  int ch = q * 256 + tid;              // dest chunk id 0..1023
  int c   = ch & 15;
  int g   = (ch >> 4) & 3;
  int pc  = (ch >> 6) & 1;
  int h   = (ch >> 7) & 1;
  int cf  = (ch >> 8) & 1;
  int p   = (ch >> 9) & 1;
  int col = p * 32 + cf * 16 + c;
  int src = col * 256 + h * 128 + g * 32 + pc * 16;
  __builtin_amdgcn_global_load_lds(
      (const __attribute__((address_space(1))) void*)((const char*)src_base + (size_t)col0 * 256 + src),
      (__attribute__((address_space(3))) void*)(dstBase + ch * 16),
      16, 0, 0);
}

// MX-K128 GEMM+LSE, R19 skeleton with HALVED wave panels (32 rows/wave):
// per-wave total ~110 regs (vs R19's 160) -> 4 waves/SIMD feasible, and
// BROWS=128 doubles the grid to 1024 blocks -> 3 blocks/CU (LDS 144 KB)
// = 3 independent barrier groups covering each other's tile-boundary
// drains. Same NT=8 / 3-buffer / counted-vmcnt(4) schedule as R19.
__global__ __launch_bounds__(256, 2) void gemm_lse_kernel(
    const unsigned char* __restrict__ qf8, const unsigned char* __restrict__ rf8,
    float* __restrict__ row_sum) {
  __shared__ __attribute__((aligned(16))) unsigned char Bl[3 * TS];  // 48 KB

  const int tid  = threadIdx.x;
  const int lane = tid & 63;
  const int wid  = tid >> 6;            // 4 waves, each owns 32 rows
  const int g = lane >> 4, c = lane & 15;
  const int row0  = blockIdx.x * BROWS;
  const int col00 = blockIdx.y * (NT * BN);
  const unsigned char* Rb = rf8;

  // A fragments FIRST (oldest in vmcnt order), then stage tiles 0 and 1 —
  // the pre-loop vmcnt(4) completes av+tile0 and keeps tile1 in flight.
  i32x8 av[2][2];
  const char* Ab = (const char*)qf8;
  #pragma unroll
  for (int m = 0; m < 2; ++m) {
    size_t rb0 = (size_t)(row0 + wid * 32 + m * 16 + c) * 256;
    #pragma unroll
    for (int h = 0; h < 2; ++h) {
      const char* p = Ab + rb0 + h * 128 + g * 32;
      av[m][h] = cat8(*(const i32x4*)(p), *(const i32x4*)(p + 16));
    }
  }
  #pragma unroll
  for (int q = 0; q < 4; ++q) stage_quarter((char*)Bl,      Rb, col00,      q, tid);
  #pragma unroll
  for (int q = 0; q < 4; ++q) stage_quarter((char*)Bl + TS, Rb, col00 + BN, q, tid);

  float rs[8];
  #pragma unroll
  for (int k = 0; k < 8; ++k) rs[k] = 0.0f;

  // tile 0 resident; tile 1's 4 loads stay in flight
  asm volatile("s_waitcnt vmcnt(4)" ::: "memory");
  __builtin_amdgcn_s_barrier();

  int rb = 0;            // read-buffer byte base (t % 3)
  int wb = 2 * TS;       // write-buffer byte base ((t+2) % 3)
  #pragma unroll 1       // R18 lesson: unrolling blows the live-range budget
  for (int t = 0; t < NT; ++t) {
    const char* lbase = (const char*)Bl + rb + lane * 16;
    int scol = col00 + (t + 2) * BN;  // tail stages read garbage inside d_ws
                                      // into a buffer that is never consumed
    #pragma unroll
    for (int p = 0; p < 2; ++p) {
      // issue this phase's half of tile t+2's staging
      stage_quarter((char*)Bl + wb, Rb, scol, 2 * p,     tid);
      stage_quarter((char*)Bl + wb, Rb, scol, 2 * p + 1, tid);

      // B fragments: all reads are lbase + compile-time immediate
      i32x8 bv[2][2];
      #pragma unroll
      for (int cf = 0; cf < 2; ++cf)
        #pragma unroll
        for (int h = 0; h < 2; ++h) {
          const int off = (p * 8 + cf * 4 + h * 2) * 1024;
          bv[cf][h] = cat8(*(const i32x4*)(lbase + off),
                           *(const i32x4*)(lbase + off + 1024));
        }

      f32x4 acc[2][2];
      const f32x4 zero = {0.f, 0.f, 0.f, 0.f};
      #pragma unroll
      for (int m = 0; m < 2; ++m) { acc[m][0] = zero; acc[m][1] = zero; }
      __builtin_amdgcn_s_setprio(1);
      #pragma unroll
      for (int m = 0; m < 2; ++m)
        #pragma unroll
        for (int cf = 0; cf < 2; ++cf) {
          acc[m][cf] = mfma_mx(av[m][0], bv[cf][0], acc[m][cf]);
          acc[m][cf] = mfma_mx(av[m][1], bv[cf][1], acc[m][cf]);
        }
      __builtin_amdgcn_s_setprio(0);

      // dot already includes log2(e): bare exp2. C layout: col = p*32+cf*16+c,
      // row = m*16 + g*4 + jj.
      #pragma unroll
      for (int m = 0; m < 2; ++m)
        #pragma unroll
        for (int jj = 0; jj < 4; ++jj)
          rs[m * 4 + jj] += exp2_hw(acc[m][0][jj]) + exp2_hw(acc[m][1][jj]);
    }

    // tile boundary: tile t+1 resident, this tile's 4 loads stay in flight
    asm volatile("s_waitcnt vmcnt(4)" ::: "memory");
    __builtin_amdgcn_s_barrier();

    rb += TS; if (rb == 3 * TS) rb = 0;
    wb += TS; if (wb == 3 * TS) wb = 0;
  }

  asm volatile("s_waitcnt vmcnt(0)" ::: "memory");  // drain tail garbage loads

  // reduce the 16 column-lanes holding the same row, one atomic per row
  #pragma unroll
  for (int k = 0; k < 8; ++k) {
    float v = rs[k];
    v += __shfl_xor(v, 1);
    v += __shfl_xor(v, 2);
    v += __shfl_xor(v, 4);
    v += __shfl_xor(v, 8);
    if (c == 0) {
      int row = row0 + wid * 32 + (k >> 2) * 16 + g * 4 + (k & 3);
      atomicAdd(&row_sum[row], v);
    }
  }
}

// 32 blocks x 256 threads, one row per thread, one atomicAdd per block
// (prep zeroed out[0]).
__global__ __launch_bounds__(256) void finalize_kernel(
    const float* __restrict__ row_sum, const float* __restrict__ pos,
    float* __restrict__ out) {
  int i = blockIdx.x * 256 + threadIdx.x;
  float s = __logf(row_sum[i]) - pos[i];
  #pragma unroll
  for (int m = 1; m < 64; m <<= 1) s += __shfl_xor(s, m);
  __shared__ float red[4];
  if ((threadIdx.x & 63) == 0) red[threadIdx.x >> 6] = s;
  __syncthreads();
  if (threadIdx.x == 0)
    atomicAdd(out, red[0] + red[1] + red[2] + red[3]);  // -loss = sum(lse-pos)
}

extern "C" void kernel_launch(void* const* d_in, const int* in_sizes, int n_in,
                              void* d_out, int out_size, void* d_ws, size_t ws_size,
                              hipStream_t stream) {
  const float* q = (const float*)d_in[0];
  const float* r = (const float*)d_in[1];
  int n = in_sizes[0] / DDIM;  // 8192

  char* w = (char*)d_ws;
  size_t f8Bytes = (size_t)n * DDIM;
  unsigned char* qf8 = (unsigned char*)w;
  unsigned char* rf8 = (unsigned char*)(w + f8Bytes);
  float* pos     = (float*)(w + 2 * f8Bytes);
  float* row_sum = pos + n;

  prep_kernel<<<n / 4, 256, 0, stream>>>(q, r, qf8, rf8, pos, row_sum,
                                         (float*)d_out);

  dim3 grid(n / BROWS, n / (NT * BN));   // 64 x 16 = 1024 blocks (3/CU)
  gemm_lse_kernel<<<grid, 256, 0, stream>>>(qf8, rf8, row_sum);

  finalize_kernel<<<n / 256, 256, 0, stream>>>(row_sum, pos, (float*)d_out);
}

// Round 24
// 36.750 us; speedup vs baseline: 1.4241x; 1.0425x over previous
//
#include <hip/hip_runtime.h>
#include <hip/hip_bf16.h>

#define DDIM   256    // K (feature dim)
#define BROWS  256    // block output rows (4 waves x 64 rows)
#define BN      32    // cols per N-tile (8 KB)
#define NT       8    // N-tiles per block -> 256-col chunk
#define TS   (BN * DDIM)   // 8 KB per buffer
#define SQRT_LOG2E 1.2011224087864498f   // sqrt(log2(e)); dot *= log2(e)

typedef float f32x4 __attribute__((ext_vector_type(4)));
typedef int   i32x4 __attribute__((ext_vector_type(4)));
typedef int   i32x8 __attribute__((ext_vector_type(8)));

// v_exp_f32: D = 2^S0 (hardware transcendental)
__device__ __forceinline__ float exp2_hw(float x) {
  return __builtin_amdgcn_exp2f(x);
}

// MX-scaled fp8 MFMA, unit scales (E8M0 127 = 1.0). cbsz=0/blgp=0 -> e4m3.
__device__ __forceinline__ f32x4 mfma_mx(i32x8 a, i32x8 b, f32x4 c) {
  return __builtin_amdgcn_mfma_scale_f32_16x16x128_f8f6f4(
      a, b, c, 0, 0, 0, 0x7F7F7F7F, 0, 0x7F7F7F7F);
}

__device__ __forceinline__ i32x8 cat8(i32x4 lo, i32x4 hi) {
  return __builtin_shufflevector(lo, hi, 0, 1, 2, 3, 4, 5, 6, 7);
}

// pack 4 f32 -> 4 fp8 e4m3 bytes
__device__ __forceinline__ unsigned int pack4_fp8(float a0, float a1, float a2, float a3) {
  int v = __builtin_amdgcn_cvt_pk_fp8_f32(a0, a1, 0, false);   // bytes 0,1
  v = __builtin_amdgcn_cvt_pk_fp8_f32(a2, a3, v, true);        // bytes 2,3
  return (unsigned int)v;
}

// ---- prep: one wave per row; writes sqrt(log2e)-scaled UNIT-NORM fp8 rows
// (so the GEMM dot is s*log2e and the epilogue is a bare exp2) + exact diag.
__global__ __launch_bounds__(256) void prep_kernel(
    const float* __restrict__ q, const float* __restrict__ r,
    unsigned char* __restrict__ qf8, unsigned char* __restrict__ rf8,
    float* __restrict__ pos, float* __restrict__ row_sum,
    float* __restrict__ out) {
  if (blockIdx.x == 0 && threadIdx.x == 0) out[0] = 0.0f;  // finalize atomics
  int lane = threadIdx.x & 63, wave = threadIdx.x >> 6;
  int row = blockIdx.x * 4 + wave;
  size_t base = (size_t)row * DDIM + lane * 4;
  float4 qv = *(const float4*)(q + base);
  float4 rv = *(const float4*)(r + base);
  float qq = qv.x*qv.x + qv.y*qv.y + qv.z*qv.z + qv.w*qv.w;
  float rr = rv.x*rv.x + rv.y*rv.y + rv.z*rv.z + rv.w*rv.w;
  float qr = qv.x*rv.x + qv.y*rv.y + qv.z*rv.z + qv.w*rv.w;
  #pragma unroll
  for (int m = 1; m < 64; m <<= 1) {
    qq += __shfl_xor(qq, m);
    rr += __shfl_xor(rr, m);
    qr += __shfl_xor(qr, m);
  }
  float iq0 = 1.0f / sqrtf(qq);
  float ir0 = 1.0f / sqrtf(rr);
  float iq = iq0 * SQRT_LOG2E;
  float ir = ir0 * SQRT_LOG2E;
  unsigned int qp = pack4_fp8(qv.x*iq, qv.y*iq, qv.z*iq, qv.w*iq);
  unsigned int rp = pack4_fp8(rv.x*ir, rv.y*ir, rv.z*ir, rv.w*ir);
  *(unsigned int*)(qf8 + base) = qp;
  *(unsigned int*)(rf8 + base) = rp;
  if (lane == 0) {
    pos[row] = qr * iq0 * ir0;   // exact f32 diagonal from raw inputs
    row_sum[row] = 0.0f;
  }
}

// stage half hf (2 KB x 2) of a 32-col fp8 tile: 1 load/thread into the
// LANE-LINEAR layout: chunk (col=cf*16+c, k16=h*8+g*2+pc) at index
// (cf*4+h*2+pc)*64 + (g*16+c) -> all ds_reads are base+lane*16+imm, zero
// bank conflicts (R17-validated scheme, minus the p bit at BN=32).
// SOURCE applies the inverse permutation (rule 21).
__device__ __forceinline__ void stage_half(char* dstBase,
                                           const unsigned char* src_base,
                                           int col0, int hf, int tid) {
  int ch = hf * 256 + tid;             // dest chunk id 0..511
  int c   = ch & 15;
  int g   = (ch >> 4) & 3;
  int pc  = (ch >> 6) & 1;
  int h   = (ch >> 7) & 1;
  int cf  = (ch >> 8) & 1;
  int col = cf * 16 + c;
  int src = col * 256 + h * 128 + g * 32 + pc * 16;
  __builtin_amdgcn_global_load_lds(
      (const __attribute__((address_space(1))) void*)((const char*)src_base + (size_t)col0 * 256 + src),
      (__attribute__((address_space(3))) void*)(dstBase + ch * 16),
      16, 0, 0);
}

// MX-K128 GEMM+LSE, R19 ratio at 3-blocks/CU occupancy: BN 64->32 keeps the
// per-wave shape (av 64 + acc 32 AGPR + rs 16 ~ 160 regs, 16 MFMA : 8
// ds_read per tile) and the NT=8 pipeline depth, while the grid doubles to
// 1024 blocks -> 3 blocks/CU (12 waves) so three independent barrier groups
// cover each other's tile-boundary drains (R19's 512-block grid capped at 2;
// R21 cut tile COUNT -> prologue dominated; R23 cut PANELS -> ratio halved).
__global__ __launch_bounds__(256, 2) void gemm_lse_kernel(
    const unsigned char* __restrict__ qf8, const unsigned char* __restrict__ rf8,
    float* __restrict__ row_sum) {
  __shared__ __attribute__((aligned(16))) unsigned char Bl[3 * TS];  // 24 KB

  const int tid  = threadIdx.x;
  const int lane = tid & 63;
  const int wid  = tid >> 6;            // 4 waves, each owns 64 rows
  const int g = lane >> 4, c = lane & 15;
  const int row0  = blockIdx.x * BROWS;
  const int col00 = blockIdx.y * (NT * BN);
  const unsigned char* Rb = rf8;

  // A fragments FIRST (oldest in vmcnt order), then stage tiles 0 and 1 —
  // the pre-loop vmcnt(2) completes av+tile0 and keeps tile1 in flight.
  i32x8 av[4][2];
  const char* Ab = (const char*)qf8;
  #pragma unroll
  for (int m = 0; m < 4; ++m) {
    size_t rb0 = (size_t)(row0 + wid * 64 + m * 16 + c) * 256;
    #pragma unroll
    for (int h = 0; h < 2; ++h) {
      const char* p = Ab + rb0 + h * 128 + g * 32;
      av[m][h] = cat8(*(const i32x4*)(p), *(const i32x4*)(p + 16));
    }
  }
  #pragma unroll
  for (int hf = 0; hf < 2; ++hf) stage_half((char*)Bl,      Rb, col00,      hf, tid);
  #pragma unroll
  for (int hf = 0; hf < 2; ++hf) stage_half((char*)Bl + TS, Rb, col00 + BN, hf, tid);

  float rs[16];
  #pragma unroll
  for (int k = 0; k < 16; ++k) rs[k] = 0.0f;

  // tile 0 resident; tile 1's 2 loads stay in flight
  asm volatile("s_waitcnt vmcnt(2)" ::: "memory");
  __builtin_amdgcn_s_barrier();

  int rb = 0;            // read-buffer byte base (t % 3)
  int wb = 2 * TS;       // write-buffer byte base ((t+2) % 3)
  #pragma unroll 1       // R18 lesson: unrolling blows the live-range budget
  for (int t = 0; t < NT; ++t) {
    const char* lbase = (const char*)Bl + rb + lane * 16;
    int scol = col00 + (t + 2) * BN;  // tail stages read garbage inside d_ws
                                      // into a buffer that is never consumed
    // issue tile t+2's staging (2 loads/thread)
    stage_half((char*)Bl + wb, Rb, scol, 0, tid);
    stage_half((char*)Bl + wb, Rb, scol, 1, tid);

    // B fragments: all reads are lbase + compile-time immediate
    i32x8 bv[2][2];
    #pragma unroll
    for (int cf = 0; cf < 2; ++cf)
      #pragma unroll
      for (int h = 0; h < 2; ++h) {
        const int off = (cf * 4 + h * 2) * 1024;
        bv[cf][h] = cat8(*(const i32x4*)(lbase + off),
                         *(const i32x4*)(lbase + off + 1024));
      }

    f32x4 acc[4][2];
    const f32x4 zero = {0.f, 0.f, 0.f, 0.f};
    #pragma unroll
    for (int m = 0; m < 4; ++m) { acc[m][0] = zero; acc[m][1] = zero; }
    __builtin_amdgcn_s_setprio(1);
    #pragma unroll
    for (int m = 0; m < 4; ++m)
      #pragma unroll
      for (int cf = 0; cf < 2; ++cf) {
        acc[m][cf] = mfma_mx(av[m][0], bv[cf][0], acc[m][cf]);
        acc[m][cf] = mfma_mx(av[m][1], bv[cf][1], acc[m][cf]);
      }
    __builtin_amdgcn_s_setprio(0);

    // dot already includes log2(e): bare exp2. C layout: col = cf*16+c,
    // row = m*16 + g*4 + jj.
    #pragma unroll
    for (int m = 0; m < 4; ++m)
      #pragma unroll
      for (int jj = 0; jj < 4; ++jj)
        rs[m * 4 + jj] += exp2_hw(acc[m][0][jj]) + exp2_hw(acc[m][1][jj]);

    // tile boundary: tile t+1 resident, this tile's 2 loads stay in flight
    asm volatile("s_waitcnt vmcnt(2)" ::: "memory");
    __builtin_amdgcn_s_barrier();

    rb += TS; if (rb == 3 * TS) rb = 0;
    wb += TS; if (wb == 3 * TS) wb = 0;
  }

  asm volatile("s_waitcnt vmcnt(0)" ::: "memory");  // drain tail garbage loads

  // reduce the 16 column-lanes holding the same row, one atomic per row
  #pragma unroll
  for (int k = 0; k < 16; ++k) {
    float v = rs[k];
    v += __shfl_xor(v, 1);
    v += __shfl_xor(v, 2);
    v += __shfl_xor(v, 4);
    v += __shfl_xor(v, 8);
    if (c == 0) {
      int row = row0 + wid * 64 + (k >> 2) * 16 + g * 4 + (k & 3);
      atomicAdd(&row_sum[row], v);
    }
  }
}

// 32 blocks x 256 threads, one row per thread, one atomicAdd per block
// (prep zeroed out[0]).
__global__ __launch_bounds__(256) void finalize_kernel(
    const float* __restrict__ row_sum, const float* __restrict__ pos,
    float* __restrict__ out) {
  int i = blockIdx.x * 256 + threadIdx.x;
  float s = __logf(row_sum[i]) - pos[i];
  #pragma unroll
  for (int m = 1; m < 64; m <<= 1) s += __shfl_xor(s, m);
  __shared__ float red[4];
  if ((threadIdx.x & 63) == 0) red[threadIdx.x >> 6] = s;
  __syncthreads();
  if (threadIdx.x == 0)
    atomicAdd(out, red[0] + red[1] + red[2] + red[3]);  // -loss = sum(lse-pos)
}

extern "C" void kernel_launch(void* const* d_in, const int* in_sizes, int n_in,
                              void* d_out, int out_size, void* d_ws, size_t ws_size,
                              hipStream_t stream) {
  const float* q = (const float*)d_in[0];
  const float* r = (const float*)d_in[1];
  int n = in_sizes[0] / DDIM;  // 8192

  char* w = (char*)d_ws;
  size_t f8Bytes = (size_t)n * DDIM;
  unsigned char* qf8 = (unsigned char*)w;
  unsigned char* rf8 = (unsigned char*)(w + f8Bytes);
  float* pos     = (float*)(w + 2 * f8Bytes);
  float* row_sum = pos + n;

  prep_kernel<<<n / 4, 256, 0, stream>>>(q, r, qf8, rf8, pos, row_sum,
                                         (float*)d_out);

  dim3 grid(n / BROWS, n / (NT * BN));   // 32 x 32 = 1024 blocks (3/CU)
  gemm_lse_kernel<<<grid, 256, 0, stream>>>(qf8, rf8, row_sum);

  finalize_kernel<<<n / 256, 256, 0, stream>>>(row_sum, pos, (float*)d_out);
}